// Round 6
// baseline (166.716 us; speedup 1.0000x reference)
//
#include <hip/hip_runtime.h>
#include <hip/hip_bf16.h>

// attentionHead: out = ((x@Wqkv+b) -> Q,K,V; (QK^T)V ; @Wout + b_out)
// No softmax => (QK^T)V = Q(K^T V). Per-head M_h = K^T V is 64x64.
// out = Q_cat @ (blockdiag(M_h) @ Wout) + b_out, Q_cat = QKV[:, :768].
//
// Pipeline:
//  0. cvt:           xbf  = bf16(x)
//  1. transpose_cvt: WqkvT, WoutT
//  2. gemm8p:        QKV = xbf @ Wqkv + b_qkv   (256x192 tile, 2 merged
//                    phases per K-tile = 24 MFMA/phase, rotation swizzle,
//                    counted vmcnt(4) once per K-tile -- ledger identical
//                    to the verified 8-phase r2-r4 schedule)
//  3. ktv_part:      Mp = partial K^T V per (b,h), 4-way t-split (f32)
//  4. gemm_w2t:      W2T[b][j][:] = blockdiag(sum Mp) @ Wout (transposed)
//  5. gemm8p:        out = Q @ W2[b] + b_out  (f32)

typedef __attribute__((ext_vector_type(8))) short bf16x8;
typedef __attribute__((ext_vector_type(4))) short short4v;
typedef __attribute__((ext_vector_type(4))) float f32x4;
typedef __attribute__((ext_vector_type(4))) float float4v;

typedef __attribute__((address_space(1))) const unsigned char ga_u8;
typedef __attribute__((address_space(3))) unsigned char la_u8;

__device__ __forceinline__ unsigned short f2bf(float f) {
  union { float f; unsigned int u; } v; v.f = f;
  unsigned int u = v.u;
  return (unsigned short)((u + 0x7FFFu + ((u >> 16) & 1u)) >> 16);  // RNE
}
__device__ __forceinline__ float bf2f(unsigned short s) {
  union { unsigned int u; float f; } v; v.u = ((unsigned int)s) << 16;
  return v.f;
}

// ---------------- f32 -> bf16 bulk convert ---------------------------------
__global__ __launch_bounds__(256) void cvt_f32_bf16(const float* __restrict__ in,
                                                    unsigned short* __restrict__ out) {
  const long long i = (long long)(blockIdx.x * 256 + threadIdx.x) * 8;
  float4v v0 = *(const float4v*)(in + i);
  float4v v1 = *(const float4v*)(in + i + 4);
  bf16x8 o;
  o[0] = (short)f2bf(v0[0]); o[1] = (short)f2bf(v0[1]);
  o[2] = (short)f2bf(v0[2]); o[3] = (short)f2bf(v0[3]);
  o[4] = (short)f2bf(v1[0]); o[5] = (short)f2bf(v1[1]);
  o[6] = (short)f2bf(v1[2]); o[7] = (short)f2bf(v1[3]);
  *(bf16x8*)(out + i) = o;
}

// ---------------- transpose + convert f32 -> bf16 --------------------------
__global__ __launch_bounds__(256) void transpose_cvt(const float* __restrict__ in,
                                                     unsigned short* __restrict__ out,
                                                     int R, int C) {
  __shared__ unsigned short tile[32][33];
  const int bx = blockIdx.x * 32;
  const int by = blockIdx.y * 32;
  const int tx = threadIdx.x & 31, ty = threadIdx.x >> 5;
  #pragma unroll
  for (int i = 0; i < 32; i += 8)
    tile[ty + i][tx] = f2bf(in[(long long)(by + ty + i) * C + bx + tx]);
  __syncthreads();
  #pragma unroll
  for (int i = 0; i < 32; i += 8)
    out[(long long)(bx + ty + i) * R + by + tx] = tile[tx][ty + i];
}

// ---------------- shared GEMM args -----------------------------------------
struct GemmArgs {
  const void* A;
  const unsigned short* BT;
  void* C;
  const float* bias;
  int M, N, K;
  int lda, ldbt, ldc;
  long long sA1, sB1, sC1;  // per-z offsets (elements)
};

// ---------------- 256x192 merged-phase GEMM --------------------------------
// D[m][n] = sum_k A[m][k]*BT[n][k] (+bias). Requires M%256==0, N%192==0,
// K%128==0, lda/ldbt%8==0, (gx*gy*gz)%8==0.
// LDS 112 KiB shorts: A halves 128x64 at buf*16384 + half*8192;
//                     B halves  96x64 at 32768 + buf*12288 + half*6144.
// Rotation swizzle both sides: LDS col' = (k + row*8)&63; all read addrs
// collapse to const + lof{0,1}.
// 2 phases per K-tile, 24 MFMA each; vmcnt(4) once per K-tile (TBV).
// Per-wave issue order identical to the verified r2-r4 8-phase ledger.

#define MFMA_(a, b, c) __builtin_amdgcn_mfma_f32_16x16x32_bf16(a, b, c, 0, 0, 0)

#define MP(bufc, half, first, STAGE1, STAGE2)                                  \
  {                                                                            \
    if (first) {                                                               \
      _Pragma("unroll")                                                        \
      for (int nf = 0; nf < 3; ++nf) {                                         \
        bfr[nf][0] = *(const bf16x8*)&L[32768 + (bufc) * 12288 + bhB +         \
                                        nf * 1024 + lof0];                     \
        bfr[nf][1] = *(const bf16x8*)&L[32768 + (bufc) * 12288 + bhB +         \
                                        nf * 1024 + lof1];                     \
      }                                                                        \
    }                                                                          \
    bf16x8 af[4][2];                                                           \
    _Pragma("unroll")                                                          \
    for (int rj = 0; rj < 4; ++rj) {                                           \
      af[rj][0] = *(const bf16x8*)&L[(bufc) * 16384 + wmA +                    \
                                     ((half) * 4 + rj) * 1024 + lof0];         \
      af[rj][1] = *(const bf16x8*)&L[(bufc) * 16384 + wmA +                    \
                                     ((half) * 4 + rj) * 1024 + lof1];         \
    }                                                                          \
    STAGE1;                                                                    \
    STAGE2;                                                                    \
    if (first) asm volatile("s_waitcnt lgkmcnt(8)" ::: "memory");              \
    __builtin_amdgcn_s_barrier();                                              \
    asm volatile("s_waitcnt lgkmcnt(0)" ::: "memory");                         \
    __builtin_amdgcn_s_setprio(1);                                             \
    _Pragma("unroll")                                                          \
    for (int nf = 0; nf < 3; ++nf)                                             \
      _Pragma("unroll")                                                        \
      for (int rj = 0; rj < 4; ++rj)                                           \
        acc[(half) * 4 + rj][nf] =                                             \
            MFMA_(af[rj][0], bfr[nf][0], acc[(half) * 4 + rj][nf]);            \
    _Pragma("unroll")                                                          \
    for (int nf = 0; nf < 3; ++nf)                                             \
      _Pragma("unroll")                                                        \
      for (int rj = 0; rj < 4; ++rj)                                           \
        acc[(half) * 4 + rj][nf] =                                             \
            MFMA_(af[rj][1], bfr[nf][1], acc[(half) * 4 + rj][nf]);            \
    __builtin_amdgcn_s_setprio(0);                                             \
  }

#define TB  { __builtin_amdgcn_s_barrier(); asm volatile("" ::: "memory"); }
#define TBV { asm volatile("s_waitcnt vmcnt(4)" ::: "memory");                 \
              __builtin_amdgcn_s_barrier(); asm volatile("" ::: "memory"); }

template <bool OUT_F32, bool BIAS>
__global__ __launch_bounds__(512, 2) void gemm8p(GemmArgs g) {
  __shared__ unsigned short L[57344];  // 112 KiB

  // bijective XCD swizzle over flattened (z,y,x); requires nwg%8==0
  const int gx = gridDim.x, gy = gridDim.y;
  const int nwg = gx * gy * gridDim.z;
  int flat = (blockIdx.z * gy + blockIdx.y) * gx + blockIdx.x;
  flat = (flat & 7) * (nwg >> 3) + (flat >> 3);
  const int gxy = gx * gy;
  const int bz = flat / gxy;
  const int rem = flat - bz * gxy;
  const int by = rem / gx;
  const int bx = rem - by * gx;

  const long long offA = bz * g.sA1;
  const long long offB = bz * g.sB1;
  const long long offC = bz * g.sC1;
  const int bm = by * 256, bn = bx * 192;

  const int tid = threadIdx.x;
  const int lane = tid & 63, wave = tid >> 6;
  const int wm = wave >> 2, wn = wave & 3;      // 2 x 4 waves; wave tile 128x48
  const int l15 = lane & 15, l4 = lane >> 4;
  const int bhalf = wn >> 1;

  // --- loop-invariant LDS read offsets (elements) ---
  const int lof0 = l15 * 64 + (((l4 + l15) * 8) & 63);
  const int lof1 = l15 * 64 + ((32 + (l4 + l15) * 8) & 63);
  const int wmA = wm * 8192;                           // A half base (this wave)
  const int bhB = bhalf * 6144 + (wn & 1) * 3072;      // B row-group base

  // --- loop-invariant staging offsets (elements) ---
  int LA[2], DA[2], LB[2], DB[2];
  #pragma unroll
  for (int r2 = 0; r2 < 2; ++r2) {
    const int c = tid + r2 * 512;
    const int row = c >> 3, j = c & 7;
    LA[r2] = row * g.lda + ((j - row) & 7) * 8;
    DA[r2] = c * 8;
    const int cb = (c >= 768) ? c - 256 : c;  // benign redundant B chunks
    const int rb = cb >> 3, jb = cb & 7;
    LB[r2] = rb * g.ldbt + ((jb - rb) & 7) * 8;
    DB[r2] = cb * 8;
  }

  const unsigned short* Ab = (const unsigned short*)g.A + offA + (long long)bm * g.lda;
  const unsigned short* Bb = g.BT + offB + (long long)bn * g.ldbt;
  // running per-half source pointers (advance +64 elems per staged K-tile)
  const unsigned short* pA0 = Ab;
  const unsigned short* pA1 = Ab + 128LL * g.lda;
  const unsigned short* pB0 = Bb;
  const unsigned short* pB1 = Bb + 96LL * g.ldbt;

  auto stA = [&](int bufsel, int half, const unsigned short* p) {
    unsigned short* dst = &L[bufsel * 16384 + half * 8192];
    __builtin_amdgcn_global_load_lds((ga_u8*)(p + LA[0]), (la_u8*)(dst + DA[0]), 16, 0, 0);
    __builtin_amdgcn_global_load_lds((ga_u8*)(p + LA[1]), (la_u8*)(dst + DA[1]), 16, 0, 0);
  };
  auto stB = [&](int bufsel, int half, const unsigned short* p) {
    unsigned short* dst = &L[32768 + bufsel * 12288 + half * 6144];
    __builtin_amdgcn_global_load_lds((ga_u8*)(p + LB[0]), (la_u8*)(dst + DB[0]), 16, 0, 0);
    __builtin_amdgcn_global_load_lds((ga_u8*)(p + LB[1]), (la_u8*)(dst + DB[1]), 16, 0, 0);
  };

  const f32x4 fz = {0.f, 0.f, 0.f, 0.f};
  f32x4 acc[8][3];
  #pragma unroll
  for (int i = 0; i < 8; ++i)
    #pragma unroll
    for (int j = 0; j < 3; ++j) acc[i][j] = fz;
  bf16x8 bfr[3][2];

  // prologue: tile0 A+B into buf0, tile1 B into buf1 -> 12 loads;
  // drain tile0 (8), leave B(1) (4) in flight.  (ledger identical to r2-r4)
  stA(0, 0, pA0); pA0 += 64;
  stA(0, 1, pA1); pA1 += 64;
  stB(0, 0, pB0); pB0 += 64;
  stB(0, 1, pB1); pB1 += 64;
  stB(1, 0, pB0); pB0 += 64;
  stB(1, 1, pB1); pB1 += 64;
  asm volatile("s_waitcnt vmcnt(4)" ::: "memory");
  __builtin_amdgcn_s_barrier();
  asm volatile("" ::: "memory");

  const int nt2 = g.K >> 7;
  for (int i = 0; i < nt2; ++i) {
    // K-tile 2i from buf0; stage A(2i+1)->buf1, then B(2i+2)->buf0
    MP(0, 0, true,  { stA(1, 0, pA0); pA0 += 64; },
                    { stA(1, 1, pA1); pA1 += 64; })  TB
    MP(0, 1, false, { stB(0, 0, pB0); pB0 += 64; },
                    { stB(0, 1, pB1); pB1 += 64; })  TBV
    // K-tile 2i+1 from buf1; stage A(2i+2)->buf0, then B(2i+3)->buf1
    MP(1, 0, true,  { stA(0, 0, pA0); pA0 += 64; },
                    { stA(0, 1, pA1); pA1 += 64; })  TB
    MP(1, 1, false, { stB(1, 0, pB0); pB0 += 64; },
                    { stB(1, 1, pB1); pB1 += 64; })  TBV
  }

  // epilogue: C/D layout col=lane&15, row=(lane>>4)*4+ii
  const int row0 = bm + wm * 128 + l4 * 4;
  const int col0 = bn + wn * 48 + l15;
  #pragma unroll
  for (int mf = 0; mf < 8; ++mf) {
    #pragma unroll
    for (int nf = 0; nf < 3; ++nf) {
      const int col = col0 + nf * 16;
      const float bv = BIAS ? g.bias[col] : 0.f;
      #pragma unroll
      for (int ii = 0; ii < 4; ++ii) {
        const int row = row0 + mf * 16 + ii;
        const float v = acc[mf][nf][ii] + bv;
        if (OUT_F32)
          ((float*)g.C)[offC + (long long)row * g.ldc + col] = v;
        else
          ((unsigned short*)g.C)[offC + (long long)row * g.ldc + col] = f2bf(v);
      }
    }
  }
}

// ---------------- W2T: per-(b,h) 768x64x64 GEMM (fused Mp reduce) ----------
// C[j][d] = sum_e WoutT[j][h*64+e] * Mh[d][e], Mh = sum_c Mp[(z*4+c)]
__global__ __launch_bounds__(256) void gemm_w2t(const unsigned short* __restrict__ WoutT,
                                                const float* __restrict__ Mp,
                                                unsigned short* __restrict__ W2T) {
  constexpr int LDT = 72;
  __shared__ unsigned short As[128 * LDT];
  __shared__ unsigned short Bs[64 * LDT];

  const int bm = blockIdx.x * 128;       // j block (768/128 = 6)
  const int z = blockIdx.y;              // b*12 + h
  const int b = z / 12, h = z % 12;
  const int tid = threadIdx.x;
  const int lane = tid & 63, wave = tid >> 6;   // 4 waves x 32 rows
  const int l15 = lane & 15, l4 = lane >> 4;
  const int srow = tid >> 3, scg = (tid & 7) * 8;

  const unsigned short* Abase = WoutT + (long long)bm * 768 + h * 64;

  #pragma unroll
  for (int s = 0; s < 4; ++s) {
    const int row = s * 32 + srow;
    *(bf16x8*)&As[row * LDT + scg] =
        *(const bf16x8*)(Abase + (long long)row * 768 + scg);
  }
  // B: reduce 4 f32 partial chunks -> bf16
  {
    const float* mpz = Mp + (long long)z * 16384;
    const int row = tid >> 2, e0 = (tid & 3) * 16;
    float s[16];
    #pragma unroll
    for (int q = 0; q < 4; ++q) {
      #pragma unroll
      for (int v = 0; v < 4; ++v) {
        float4v x = *(const float4v*)&mpz[q * 4096 + row * 64 + e0 + v * 4];
        if (q == 0) {
          s[v*4+0] = x[0]; s[v*4+1] = x[1]; s[v*4+2] = x[2]; s[v*4+3] = x[3];
        } else {
          s[v*4+0] += x[0]; s[v*4+1] += x[1]; s[v*4+2] += x[2]; s[v*4+3] += x[3];
        }
      }
    }
    #pragma unroll
    for (int k = 0; k < 16; ++k) Bs[row * LDT + e0 + k] = f2bf(s[k]);
  }
  __syncthreads();

  const f32x4 fz = {0.f, 0.f, 0.f, 0.f};
  f32x4 acc[2][4];
  #pragma unroll
  for (int i = 0; i < 2; ++i)
    #pragma unroll
    for (int j = 0; j < 4; ++j) acc[i][j] = fz;

  #pragma unroll
  for (int ks = 0; ks < 64; ks += 32) {
    const int kk = ks + l4 * 8;
    bf16x8 af[2], bfv[4];
    #pragma unroll
    for (int i = 0; i < 2; ++i)
      af[i] = *(const bf16x8*)&As[(wave * 32 + i * 16 + l15) * LDT + kk];
    #pragma unroll
    for (int i = 0; i < 4; ++i)
      bfv[i] = *(const bf16x8*)&Bs[(i * 16 + l15) * LDT + kk];
    #pragma unroll
    for (int mi = 0; mi < 2; ++mi)
      #pragma unroll
      for (int ni = 0; ni < 4; ++ni)
        acc[mi][ni] = MFMA_(af[mi], bfv[ni], acc[mi][ni]);
  }

  unsigned short* Cb = W2T + (long long)b * 589824 + h * 64;
  #pragma unroll
  for (int mi = 0; mi < 2; ++mi)
    #pragma unroll
    for (int ni = 0; ni < 4; ++ni)
      #pragma unroll
      for (int ii = 0; ii < 4; ++ii) {
        const int row = bm + wave * 32 + mi * 16 + l4 * 4 + ii;
        const int col = ni * 16 + l15;
        Cb[(long long)row * 768 + col] = f2bf(acc[mi][ni][ii]);
      }
}

// ---------------- K^T V per head, 4-way t-split ----------------------------
__global__ __launch_bounds__(256) void ktv_part(const unsigned short* __restrict__ QKV,
                                                float* __restrict__ Mp) {
  const int z = blockIdx.x;        // (b*12+h)*4 + chunk
  const int bh = z >> 2, chunk = z & 3;
  const int b = bh / 12, h = bh % 12;
  __shared__ unsigned short Ks[32 * 64];
  __shared__ unsigned short Vs[32 * 64];
  const int tid = threadIdx.x;
  const int ti = tid & 15, tj = tid >> 4;
  const int srow = tid >> 3, scg = (tid & 7) * 8;

  float acc[4][4];
  #pragma unroll
  for (int i = 0; i < 4; ++i)
    #pragma unroll
    for (int j = 0; j < 4; ++j) acc[i][j] = 0.f;

  const long long baseK = (long long)b * 1024 * 2304 + 768 + h * 64;
  const int t0 = chunk * 256;
  for (int tc = t0; tc < t0 + 256; tc += 32) {
    __syncthreads();
    const long long gidx = baseK + (long long)(tc + srow) * 2304 + scg;
    *(bf16x8*)&Ks[srow * 64 + scg] = *(const bf16x8*)&QKV[gidx];
    *(bf16x8*)&Vs[srow * 64 + scg] = *(const bf16x8*)&QKV[gidx + 768];
    __syncthreads();
    #pragma unroll 8
    for (int t = 0; t < 32; ++t) {
      const short4v ka = *(const short4v*)&Ks[t * 64 + ti * 4];
      const short4v va = *(const short4v*)&Vs[t * 64 + tj * 4];
      float a0 = bf2f((unsigned short)ka[0]), a1 = bf2f((unsigned short)ka[1]);
      float a2 = bf2f((unsigned short)ka[2]), a3 = bf2f((unsigned short)ka[3]);
      float b0 = bf2f((unsigned short)va[0]), b1 = bf2f((unsigned short)va[1]);
      float b2 = bf2f((unsigned short)va[2]), b3 = bf2f((unsigned short)va[3]);
      acc[0][0] += a0 * b0; acc[0][1] += a0 * b1; acc[0][2] += a0 * b2; acc[0][3] += a0 * b3;
      acc[1][0] += a1 * b0; acc[1][1] += a1 * b1; acc[1][2] += a1 * b2; acc[1][3] += a1 * b3;
      acc[2][0] += a2 * b0; acc[2][1] += a2 * b1; acc[2][2] += a2 * b2; acc[2][3] += a2 * b3;
      acc[3][0] += a3 * b0; acc[3][1] += a3 * b1; acc[3][2] += a3 * b2; acc[3][3] += a3 * b3;
    }
  }
  float* mp = Mp + (long long)z * 4096;
  #pragma unroll
  for (int i = 0; i < 4; ++i) {
    float4v v = {acc[i][0], acc[i][1], acc[i][2], acc[i][3]};
    *(float4v*)&mp[(ti * 4 + i) * 64 + tj * 4] = v;
  }
}

// ---------------------------------------------------------------------------
extern "C" void kernel_launch(void* const* d_in, const int* in_sizes, int n_in,
                              void* d_out, int out_size, void* d_ws, size_t ws_size,
                              hipStream_t stream) {
  (void)in_sizes; (void)n_in; (void)out_size; (void)ws_size;
  const float* x    = (const float*)d_in[0];  // [16384,768]
  const float* Wqkv = (const float*)d_in[1];  // [768,2304]
  const float* bqkv = (const float*)d_in[2];  // [2304]
  const float* Wout = (const float*)d_in[3];  // [768,768]
  const float* bout = (const float*)d_in[4];  // [768]
  float* out = (float*)d_out;                 // [16384,768] f32

  char* ws = (char*)d_ws;
  size_t off = 0;
  auto carve = [&](size_t bytes) {
    char* p = ws + off;
    off += (bytes + 255) & ~(size_t)255;
    return p;
  };
  unsigned short* WqkvT = (unsigned short*)carve((size_t)2304 * 768 * 2);    // 3.5 MB
  unsigned short* WoutT = (unsigned short*)carve((size_t)768 * 768 * 2);     // 1.2 MB
  unsigned short* QKV   = (unsigned short*)carve((size_t)16384 * 2304 * 2);  // 72.5 MB
  float*          Mp    = (float*)carve((size_t)768 * 4096 * 4);             // 12.6 MB
  unsigned short* xbf   = (unsigned short*)carve((size_t)16384 * 768 * 2);   // 25.2 MB
  unsigned short* W2T   = xbf;  // aliases xbf (dead after gemm1); 18 MB fits
  carve((size_t)1 << 18);       // 256 KB slack for staging-pointer overshoot
  // total ~115 MB of d_ws

  cvt_f32_bf16<<<dim3(16384 * 768 / 8 / 256), 256, 0, stream>>>(x, xbf);
  transpose_cvt<<<dim3(2304 / 32, 768 / 32), 256, 0, stream>>>(Wqkv, WqkvT, 768, 2304);
  transpose_cvt<<<dim3(768 / 32, 768 / 32), 256, 0, stream>>>(Wout, WoutT, 768, 768);

  // 1) QKV = xbf @ Wqkv + b_qkv   (grid 12*64=768 = 3 exact rounds)
  GemmArgs g1{};
  g1.A = xbf; g1.BT = WqkvT; g1.C = QKV; g1.bias = bqkv;
  g1.M = 16384; g1.N = 2304; g1.K = 768;
  g1.lda = 768; g1.ldbt = 768; g1.ldc = 2304;
  gemm8p<false, true><<<dim3(12, 64, 1), 512, 0, stream>>>(g1);

  // 2) Mp = partial K^T V per (b,h), split 4 ways over t
  ktv_part<<<dim3(768), 256, 0, stream>>>(QKV, Mp);

  // 3) W2T[b][j][h*64+d] = sum_e WoutT[j][h*64+e] * (sum Mp)[d][e]
  gemm_w2t<<<dim3(6, 192), 256, 0, stream>>>(WoutT, Mp, W2T);

  // 4) out[b] = Q[b] @ W2[b] + b_out  (grid 4*4*16=256 = 1 exact round)
  GemmArgs g3{};
  g3.A = QKV; g3.BT = W2T; g3.C = out; g3.bias = bout;
  g3.M = 1024; g3.N = 768; g3.K = 768;
  g3.lda = 2304; g3.ldbt = 768; g3.ldc = 768;
  g3.sA1 = 2359296;  // 1024*2304
  g3.sB1 = 589824;   // 768*768
  g3.sC1 = 786432;   // 1024*768
  gemm8p<true, true><<<dim3(4, 4, 16), 512, 0, stream>>>(g3);
}

// Round 7
// 165.776 us; speedup vs baseline: 1.0057x; 1.0057x over previous
//
#include <hip/hip_runtime.h>
#include <hip/hip_bf16.h>

// attentionHead: out = ((x@Wqkv+b) -> Q,K,V; (QK^T)V ; @Wout + b_out)
// No softmax => (QK^T)V = Q(K^T V). Per-head M_h = K^T V is 64x64.
// out = Q_cat @ (blockdiag(M_h) @ Wout) + b_out, Q_cat = QKV[:, :768].
//
// Pipeline:
//  0. cvt:           xbf  = bf16(x)
//  1. transpose_cvt: WqkvT, WoutT
//  2. gemm1b:        QKV = xbf @ Wqkv + b_qkv   (256x192 tile, ONE barrier per
//                    K-tile: A double-buffered, B TRIPLE-buffered so staging
//                    never targets the buffer being read; ds_reads+MFMA
//                    scheduled by compiler dependence; counted vmcnt(3))
//  3. ktv_part:      Mp = partial K^T V per (b,h), 4-way t-split (f32)
//  4. gemm_w2t:      W2T[b][j][:] = blockdiag(sum Mp) @ Wout (transposed)
//  5. gemm1b:        out = Q @ W2[b] + b_out  (f32)

typedef __attribute__((ext_vector_type(8))) short bf16x8;
typedef __attribute__((ext_vector_type(4))) short short4v;
typedef __attribute__((ext_vector_type(4))) float f32x4;
typedef __attribute__((ext_vector_type(4))) float float4v;

typedef __attribute__((address_space(1))) const unsigned char ga_u8;
typedef __attribute__((address_space(3))) unsigned char la_u8;

__device__ __forceinline__ unsigned short f2bf(float f) {
  union { float f; unsigned int u; } v; v.f = f;
  unsigned int u = v.u;
  return (unsigned short)((u + 0x7FFFu + ((u >> 16) & 1u)) >> 16);  // RNE
}
__device__ __forceinline__ float bf2f(unsigned short s) {
  union { unsigned int u; float f; } v; v.u = ((unsigned int)s) << 16;
  return v.f;
}

// ---------------- f32 -> bf16 bulk convert ---------------------------------
__global__ __launch_bounds__(256) void cvt_f32_bf16(const float* __restrict__ in,
                                                    unsigned short* __restrict__ out) {
  const long long i = (long long)(blockIdx.x * 256 + threadIdx.x) * 8;
  float4v v0 = *(const float4v*)(in + i);
  float4v v1 = *(const float4v*)(in + i + 4);
  bf16x8 o;
  o[0] = (short)f2bf(v0[0]); o[1] = (short)f2bf(v0[1]);
  o[2] = (short)f2bf(v0[2]); o[3] = (short)f2bf(v0[3]);
  o[4] = (short)f2bf(v1[0]); o[5] = (short)f2bf(v1[1]);
  o[6] = (short)f2bf(v1[2]); o[7] = (short)f2bf(v1[3]);
  *(bf16x8*)(out + i) = o;
}

// ---------------- transpose + convert f32 -> bf16 --------------------------
__global__ __launch_bounds__(256) void transpose_cvt(const float* __restrict__ in,
                                                     unsigned short* __restrict__ out,
                                                     int R, int C) {
  __shared__ unsigned short tile[32][33];
  const int bx = blockIdx.x * 32;
  const int by = blockIdx.y * 32;
  const int tx = threadIdx.x & 31, ty = threadIdx.x >> 5;
  #pragma unroll
  for (int i = 0; i < 32; i += 8)
    tile[ty + i][tx] = f2bf(in[(long long)(by + ty + i) * C + bx + tx]);
  __syncthreads();
  #pragma unroll
  for (int i = 0; i < 32; i += 8)
    out[(long long)(bx + ty + i) * R + by + tx] = tile[tx][ty + i];
}

// ---------------- shared GEMM args -----------------------------------------
struct GemmArgs {
  const void* A;
  const unsigned short* BT;
  void* C;
  const float* bias;
  int M, N, K;
  int lda, ldbt, ldc;
  long long sA1, sB1, sC1;  // per-z offsets (elements)
};

// ---------------- 256x192 one-barrier-per-K-tile GEMM ----------------------
// D[m][n] = sum_k A[m][k]*BT[n][k] (+bias). Requires M%256==0, N%192==0,
// K%64==0, lda/ldbt%8==0, (gx*gy*gz)%8==0.
// LDS 136 KiB shorts: A[2 buf][256][64] at buf*16384;
//                     B[3 buf][192][64] at 32768 + bb*12288.
// Rotation swizzle both sides: LDS col' = (k + row*8)&63; since fragment rows
// differ by multiples of 16 (16*8 % 64 == 0), all read addrs = base + lof0/1.
// Ledger: prologue stages A0,B0 (7), B1 (3); iter t stages A(t+1) (4),
// B(t+2) (3); end-of-iter outstanding = {B(t+1):3, A(t+1):4, B(t+2):3};
// vmcnt(3) drains B(t+1)+A(t+1). One barrier per K-tile.
// WAR safety: stA(t+1) targets A-buf last read at t-1; stB(t+2) targets B-buf
// (t+2)%3 = (t-1)%3, last read at t-1. Both reads completed before iter t's
// entry barrier (compiler-enforced lgkm waits precede the MFMAs that precede
// the barrier). Staging pointers overshoot by <=2 tiles into allocated slack.

#define MFMA_(a, b, c) __builtin_amdgcn_mfma_f32_16x16x32_bf16(a, b, c, 0, 0, 0)
#define TBV { asm volatile("s_waitcnt vmcnt(3)" ::: "memory");                 \
              __builtin_amdgcn_s_barrier(); asm volatile("" ::: "memory"); }

template <bool OUT_F32, bool BIAS>
__global__ __launch_bounds__(512, 2) void gemm1b(GemmArgs g) {
  __shared__ unsigned short L[69632];  // 136 KiB

  // bijective XCD swizzle over flattened (z,y,x); requires nwg%8==0
  const int gx = gridDim.x, gy = gridDim.y;
  const int nwg = gx * gy * gridDim.z;
  int flat = (blockIdx.z * gy + blockIdx.y) * gx + blockIdx.x;
  flat = (flat & 7) * (nwg >> 3) + (flat >> 3);
  const int gxy = gx * gy;
  const int bz = flat / gxy;
  const int rem = flat - bz * gxy;
  const int by = rem / gx;
  const int bx = rem - by * gx;

  const long long offA = bz * g.sA1;
  const long long offB = bz * g.sB1;
  const long long offC = bz * g.sC1;
  const int bm = by * 256, bn = bx * 192;

  const int tid = threadIdx.x;
  const int lane = tid & 63, wave = tid >> 6;
  const int wm = wave >> 2, wn = wave & 3;      // 2 x 4 waves; wave tile 128x48
  const int l15 = lane & 15, l4 = lane >> 4;

  // --- loop-invariant LDS read offsets (elements) ---
  const int lof0 = l15 * 64 + (((l4 + l15) * 8) & 63);
  const int lof1 = l15 * 64 + ((32 + (l4 + l15) * 8) & 63);
  const int wmA = wm * 8192;        // A half base within A-buf (rows wm*128..)
  const int wnB = wn * 3072;        // B row-group base within B-buf

  // --- loop-invariant staging offsets (elements) ---
  int LA[4], DA[4], LB[3], DB[3];
  #pragma unroll
  for (int r = 0; r < 4; ++r) {
    const int c = tid + r * 512;                 // A chunks 0..2047 (rows 0..255)
    const int row = c >> 3, j = c & 7;
    LA[r] = row * g.lda + ((j - row) & 7) * 8;   // inverse rotation on source
    DA[r] = c * 8;
  }
  #pragma unroll
  for (int r = 0; r < 3; ++r) {
    const int c = tid + r * 512;                 // B chunks 0..1535 (rows 0..191)
    const int row = c >> 3, j = c & 7;
    LB[r] = row * g.ldbt + ((j - row) & 7) * 8;
    DB[r] = c * 8;
  }

  const unsigned short* Ab = (const unsigned short*)g.A + offA + (long long)bm * g.lda;
  const unsigned short* Bb = g.BT + offB + (long long)bn * g.ldbt;

  auto stA = [&](int bufsel, const unsigned short* p) {
    unsigned short* dst = &L[bufsel * 16384];
    #pragma unroll
    for (int r = 0; r < 4; ++r)
      __builtin_amdgcn_global_load_lds((ga_u8*)(p + LA[r]), (la_u8*)(dst + DA[r]), 16, 0, 0);
  };
  auto stB = [&](int bb, const unsigned short* p) {
    unsigned short* dst = &L[32768 + bb * 12288];
    #pragma unroll
    for (int r = 0; r < 3; ++r)
      __builtin_amdgcn_global_load_lds((ga_u8*)(p + LB[r]), (la_u8*)(dst + DB[r]), 16, 0, 0);
  };

  const f32x4 fz = {0.f, 0.f, 0.f, 0.f};
  f32x4 acc[8][3];
  #pragma unroll
  for (int i = 0; i < 8; ++i)
    #pragma unroll
    for (int j = 0; j < 3; ++j) acc[i][j] = fz;

  // running staging source pointers (k-offset advances 64/tile)
  const unsigned short* pA = Ab;
  const unsigned short* pB = Bb;

  // prologue: A0,B0 (7 instr), B1 (3 instr) -> 10 outstanding; drain to 3.
  stA(0, pA); pA += 64;
  stB(0, pB); pB += 64;
  stB(1, pB); pB += 64;
  TBV

  const int NT = g.K >> 6;
  int bufc = 0, bbr = 0, bbs = 2;  // read A-buf, read B-buf, stage B-buf
  for (int t = 0; t < NT; ++t) {
    const unsigned short* As_ = &L[bufc * 16384 + wmA];
    const unsigned short* Bs_ = &L[32768 + bbr * 12288 + wnB];

    // ---- issue all LDS reads for this K-tile (compiler inserts lgkm waits) --
    bf16x8 bfr[3][2], af[8][2];
    #pragma unroll
    for (int nf = 0; nf < 3; ++nf) {
      bfr[nf][0] = *(const bf16x8*)&Bs_[nf * 1024 + lof0];
      bfr[nf][1] = *(const bf16x8*)&Bs_[nf * 1024 + lof1];
    }
    #pragma unroll
    for (int rj = 0; rj < 8; ++rj) {
      af[rj][0] = *(const bf16x8*)&As_[rj * 1024 + lof0];
      af[rj][1] = *(const bf16x8*)&As_[rj * 1024 + lof1];
    }

    // ---- issue next-tile staging (no WAR: targets not read this tile) ------
    stA(bufc ^ 1, pA); pA += 64;   // A(t+1)
    stB(bbs, pB); pB += 64;        // B(t+2)

    // ---- MFMA: 48, k-pass-major (dependent-pair distance 24) ---------------
    __builtin_amdgcn_s_setprio(1);
    #pragma unroll
    for (int k = 0; k < 2; ++k)
      #pragma unroll
      for (int nf = 0; nf < 3; ++nf)
        #pragma unroll
        for (int rj = 0; rj < 8; ++rj)
          acc[rj][nf] = MFMA_(af[rj][k], bfr[nf][k], acc[rj][nf]);
    __builtin_amdgcn_s_setprio(0);

    TBV
    bufc ^= 1;
    bbr = (bbr == 2) ? 0 : bbr + 1;
    bbs = (bbs == 2) ? 0 : bbs + 1;
  }

  // epilogue: C/D layout col=lane&15, row=(lane>>4)*4+ii
  const int row0 = bm + wm * 128 + l4 * 4;
  const int col0 = bn + wn * 48 + l15;
  #pragma unroll
  for (int mf = 0; mf < 8; ++mf) {
    #pragma unroll
    for (int nf = 0; nf < 3; ++nf) {
      const int col = col0 + nf * 16;
      const float bv = BIAS ? g.bias[col] : 0.f;
      #pragma unroll
      for (int ii = 0; ii < 4; ++ii) {
        const int row = row0 + mf * 16 + ii;
        const float v = acc[mf][nf][ii] + bv;
        if (OUT_F32)
          ((float*)g.C)[offC + (long long)row * g.ldc + col] = v;
        else
          ((unsigned short*)g.C)[offC + (long long)row * g.ldc + col] = f2bf(v);
      }
    }
  }
}

// ---------------- W2T: per-(b,h) 768x64x64 GEMM (fused Mp reduce) ----------
// C[j][d] = sum_e WoutT[j][h*64+e] * Mh[d][e], Mh = sum_c Mp[(z*4+c)]
__global__ __launch_bounds__(256) void gemm_w2t(const unsigned short* __restrict__ WoutT,
                                                const float* __restrict__ Mp,
                                                unsigned short* __restrict__ W2T) {
  constexpr int LDT = 72;
  __shared__ unsigned short As[128 * LDT];
  __shared__ unsigned short Bs[64 * LDT];

  const int bm = blockIdx.x * 128;       // j block (768/128 = 6)
  const int z = blockIdx.y;              // b*12 + h
  const int b = z / 12, h = z % 12;
  const int tid = threadIdx.x;
  const int lane = tid & 63, wave = tid >> 6;   // 4 waves x 32 rows
  const int l15 = lane & 15, l4 = lane >> 4;
  const int srow = tid >> 3, scg = (tid & 7) * 8;

  const unsigned short* Abase = WoutT + (long long)bm * 768 + h * 64;

  #pragma unroll
  for (int s = 0; s < 4; ++s) {
    const int row = s * 32 + srow;
    *(bf16x8*)&As[row * LDT + scg] =
        *(const bf16x8*)(Abase + (long long)row * 768 + scg);
  }
  // B: reduce 4 f32 partial chunks -> bf16
  {
    const float* mpz = Mp + (long long)z * 16384;
    const int row = tid >> 2, e0 = (tid & 3) * 16;
    float s[16];
    #pragma unroll
    for (int q = 0; q < 4; ++q) {
      #pragma unroll
      for (int v = 0; v < 4; ++v) {
        float4v x = *(const float4v*)&mpz[q * 4096 + row * 64 + e0 + v * 4];
        if (q == 0) {
          s[v*4+0] = x[0]; s[v*4+1] = x[1]; s[v*4+2] = x[2]; s[v*4+3] = x[3];
        } else {
          s[v*4+0] += x[0]; s[v*4+1] += x[1]; s[v*4+2] += x[2]; s[v*4+3] += x[3];
        }
      }
    }
    #pragma unroll
    for (int k = 0; k < 16; ++k) Bs[row * LDT + e0 + k] = f2bf(s[k]);
  }
  __syncthreads();

  const f32x4 fz = {0.f, 0.f, 0.f, 0.f};
  f32x4 acc[2][4];
  #pragma unroll
  for (int i = 0; i < 2; ++i)
    #pragma unroll
    for (int j = 0; j < 4; ++j) acc[i][j] = fz;

  #pragma unroll
  for (int ks = 0; ks < 64; ks += 32) {
    const int kk = ks + l4 * 8;
    bf16x8 af[2], bfv[4];
    #pragma unroll
    for (int i = 0; i < 2; ++i)
      af[i] = *(const bf16x8*)&As[(wave * 32 + i * 16 + l15) * LDT + kk];
    #pragma unroll
    for (int i = 0; i < 4; ++i)
      bfv[i] = *(const bf16x8*)&Bs[(i * 16 + l15) * LDT + kk];
    #pragma unroll
    for (int mi = 0; mi < 2; ++mi)
      #pragma unroll
      for (int ni = 0; ni < 4; ++ni)
        acc[mi][ni] = MFMA_(af[mi], bfv[ni], acc[mi][ni]);
  }

  unsigned short* Cb = W2T + (long long)b * 589824 + h * 64;
  #pragma unroll
  for (int mi = 0; mi < 2; ++mi)
    #pragma unroll
    for (int ni = 0; ni < 4; ++ni)
      #pragma unroll
      for (int ii = 0; ii < 4; ++ii) {
        const int row = bm + wave * 32 + mi * 16 + l4 * 4 + ii;
        const int col = ni * 16 + l15;
        Cb[(long long)row * 768 + col] = f2bf(acc[mi][ni][ii]);
      }
}

// ---------------- K^T V per head, 4-way t-split ----------------------------
__global__ __launch_bounds__(256) void ktv_part(const unsigned short* __restrict__ QKV,
                                                float* __restrict__ Mp) {
  const int z = blockIdx.x;        // (b*12+h)*4 + chunk
  const int bh = z >> 2, chunk = z & 3;
  const int b = bh / 12, h = bh % 12;
  __shared__ unsigned short Ks[32 * 64];
  __shared__ unsigned short Vs[32 * 64];
  const int tid = threadIdx.x;
  const int ti = tid & 15, tj = tid >> 4;
  const int srow = tid >> 3, scg = (tid & 7) * 8;

  float acc[4][4];
  #pragma unroll
  for (int i = 0; i < 4; ++i)
    #pragma unroll
    for (int j = 0; j < 4; ++j) acc[i][j] = 0.f;

  const long long baseK = (long long)b * 1024 * 2304 + 768 + h * 64;
  const int t0 = chunk * 256;
  for (int tc = t0; tc < t0 + 256; tc += 32) {
    __syncthreads();
    const long long gidx = baseK + (long long)(tc + srow) * 2304 + scg;
    *(bf16x8*)&Ks[srow * 64 + scg] = *(const bf16x8*)&QKV[gidx];
    *(bf16x8*)&Vs[srow * 64 + scg] = *(const bf16x8*)&QKV[gidx + 768];
    __syncthreads();
    #pragma unroll 8
    for (int t = 0; t < 32; ++t) {
      const short4v ka = *(const short4v*)&Ks[t * 64 + ti * 4];
      const short4v va = *(const short4v*)&Vs[t * 64 + tj * 4];
      float a0 = bf2f((unsigned short)ka[0]), a1 = bf2f((unsigned short)ka[1]);
      float a2 = bf2f((unsigned short)ka[2]), a3 = bf2f((unsigned short)ka[3]);
      float b0 = bf2f((unsigned short)va[0]), b1 = bf2f((unsigned short)va[1]);
      float b2 = bf2f((unsigned short)va[2]), b3 = bf2f((unsigned short)va[3]);
      acc[0][0] += a0 * b0; acc[0][1] += a0 * b1; acc[0][2] += a0 * b2; acc[0][3] += a0 * b3;
      acc[1][0] += a1 * b0; acc[1][1] += a1 * b1; acc[1][2] += a1 * b2; acc[1][3] += a1 * b3;
      acc[2][0] += a2 * b0; acc[2][1] += a2 * b1; acc[2][2] += a2 * b2; acc[2][3] += a2 * b3;
      acc[3][0] += a3 * b0; acc[3][1] += a3 * b1; acc[3][2] += a3 * b2; acc[3][3] += a3 * b3;
    }
  }
  float* mp = Mp + (long long)z * 4096;
  #pragma unroll
  for (int i = 0; i < 4; ++i) {
    float4v v = {acc[i][0], acc[i][1], acc[i][2], acc[i][3]};
    *(float4v*)&mp[(ti * 4 + i) * 64 + tj * 4] = v;
  }
}

// ---------------------------------------------------------------------------
extern "C" void kernel_launch(void* const* d_in, const int* in_sizes, int n_in,
                              void* d_out, int out_size, void* d_ws, size_t ws_size,
                              hipStream_t stream) {
  (void)in_sizes; (void)n_in; (void)out_size; (void)ws_size;
  const float* x    = (const float*)d_in[0];  // [16384,768]
  const float* Wqkv = (const float*)d_in[1];  // [768,2304]
  const float* bqkv = (const float*)d_in[2];  // [2304]
  const float* Wout = (const float*)d_in[3];  // [768,768]
  const float* bout = (const float*)d_in[4];  // [768]
  float* out = (float*)d_out;                 // [16384,768] f32

  char* ws = (char*)d_ws;
  size_t off = 0;
  auto carve = [&](size_t bytes) {
    char* p = ws + off;
    off += (bytes + 255) & ~(size_t)255;
    return p;
  };
  unsigned short* WqkvT = (unsigned short*)carve((size_t)2304 * 768 * 2);    // 3.5 MB
  unsigned short* WoutT = (unsigned short*)carve((size_t)768 * 768 * 2);     // 1.2 MB
  unsigned short* QKV   = (unsigned short*)carve((size_t)16384 * 2304 * 2);  // 72.5 MB
  float*          Mp    = (float*)carve((size_t)768 * 4096 * 4);             // 12.6 MB
  unsigned short* xbf   = (unsigned short*)carve((size_t)16384 * 768 * 2);   // 25.2 MB
  unsigned short* W2T   = xbf;  // aliases xbf (dead after gemm1); 18 MB fits
  carve((size_t)1 << 18);       // 256 KB slack for staging-pointer overshoot
  // total ~115 MB of d_ws

  cvt_f32_bf16<<<dim3(16384 * 768 / 8 / 256), 256, 0, stream>>>(x, xbf);
  transpose_cvt<<<dim3(2304 / 32, 768 / 32), 256, 0, stream>>>(Wqkv, WqkvT, 768, 2304);
  transpose_cvt<<<dim3(768 / 32, 768 / 32), 256, 0, stream>>>(Wout, WoutT, 768, 768);

  // 1) QKV = xbf @ Wqkv + b_qkv   (grid 12*64=768 = 3 exact rounds)
  GemmArgs g1{};
  g1.A = xbf; g1.BT = WqkvT; g1.C = QKV; g1.bias = bqkv;
  g1.M = 16384; g1.N = 2304; g1.K = 768;
  g1.lda = 768; g1.ldbt = 768; g1.ldc = 2304;
  gemm1b<false, true><<<dim3(12, 64, 1), 512, 0, stream>>>(g1);

  // 2) Mp = partial K^T V per (b,h), split 4 ways over t
  ktv_part<<<dim3(768), 256, 0, stream>>>(QKV, Mp);

  // 3) W2T[b][j][h*64+d] = sum_e WoutT[j][h*64+e] * (sum Mp)[d][e]
  gemm_w2t<<<dim3(6, 192), 256, 0, stream>>>(WoutT, Mp, W2T);

  // 4) out[b] = Q[b] @ W2[b] + b_out  (grid 4*4*16=256 = 1 exact round)
  GemmArgs g3{};
  g3.A = QKV; g3.BT = W2T; g3.C = out; g3.bias = bout;
  g3.M = 1024; g3.N = 768; g3.K = 768;
  g3.lda = 2304; g3.ldbt = 768; g3.ldc = 768;
  g3.sA1 = 2359296;  // 1024*2304
  g3.sB1 = 589824;   // 768*768
  g3.sC1 = 786432;   // 1024*768
  gemm1b<true, true><<<dim3(4, 4, 16), 512, 0, stream>>>(g3);
}

// Round 8
// 133.558 us; speedup vs baseline: 1.2483x; 1.2412x over previous
//
#include <hip/hip_runtime.h>
#include <hip/hip_bf16.h>

// attentionHead: out = ((x@Wqkv+b) -> Q,K,V; (QK^T)V ; @Wout + b_out)
// No softmax => (QK^T)V = Q(K^T V). Per-head M_h = K^T V is 64x64.
// out = Q @ (blockdiag(M_h) @ Wout) + b_out.
//
// Pipeline:
//  0. cvt:           xbf = bf16(x)
//  1. transpose_cvt: WqkvT, WoutT
//  2. gemm1b<1>:     {Q row-major, KT, VT transposed} = xbf @ Wqkv + b_qkv
//                    (256x192 tile, 1 barrier/K-tile, k-half register pipeline)
//  3. ktv_mfma:      Mh[bh] = KT[bh] @ VT[bh]^T  (M=64,N=64,K=1024, MFMA)
//  4. gemm_w2t:      W2T[b][j][:] = blockdiag(Mh) @ Wout (transposed)
//  5. gemm1b<2>:     out = Q @ W2[b] + b_out  (f32)

typedef __attribute__((ext_vector_type(8))) short bf16x8;
typedef __attribute__((ext_vector_type(4))) short short4v;
typedef __attribute__((ext_vector_type(4))) float f32x4;
typedef __attribute__((ext_vector_type(4))) float float4v;

typedef __attribute__((address_space(1))) const unsigned char ga_u8;
typedef __attribute__((address_space(3))) unsigned char la_u8;

__device__ __forceinline__ unsigned short f2bf(float f) {
  union { float f; unsigned int u; } v; v.f = f;
  unsigned int u = v.u;
  return (unsigned short)((u + 0x7FFFu + ((u >> 16) & 1u)) >> 16);  // RNE
}

// ---------------- f32 -> bf16 bulk convert ---------------------------------
__global__ __launch_bounds__(256) void cvt_f32_bf16(const float* __restrict__ in,
                                                    unsigned short* __restrict__ out) {
  const long long i = (long long)(blockIdx.x * 256 + threadIdx.x) * 8;
  float4v v0 = *(const float4v*)(in + i);
  float4v v1 = *(const float4v*)(in + i + 4);
  bf16x8 o;
  o[0] = (short)f2bf(v0[0]); o[1] = (short)f2bf(v0[1]);
  o[2] = (short)f2bf(v0[2]); o[3] = (short)f2bf(v0[3]);
  o[4] = (short)f2bf(v1[0]); o[5] = (short)f2bf(v1[1]);
  o[6] = (short)f2bf(v1[2]); o[7] = (short)f2bf(v1[3]);
  *(bf16x8*)(out + i) = o;
}

// ---------------- transpose + convert f32 -> bf16 --------------------------
__global__ __launch_bounds__(256) void transpose_cvt(const float* __restrict__ in,
                                                     unsigned short* __restrict__ out,
                                                     int R, int C) {
  __shared__ unsigned short tile[32][33];
  const int bx = blockIdx.x * 32;
  const int by = blockIdx.y * 32;
  const int tx = threadIdx.x & 31, ty = threadIdx.x >> 5;
  #pragma unroll
  for (int i = 0; i < 32; i += 8)
    tile[ty + i][tx] = f2bf(in[(long long)(by + ty + i) * C + bx + tx]);
  __syncthreads();
  #pragma unroll
  for (int i = 0; i < 32; i += 8)
    out[(long long)(bx + ty + i) * R + by + tx] = tile[tx][ty + i];
}

// ---------------- shared GEMM args -----------------------------------------
struct GemmArgs {
  const void* A;
  const unsigned short* BT;
  void* C;                    // OMODE1: Qbuf; OMODE2: f32 out
  unsigned short* KT;         // OMODE1 only
  unsigned short* VT;         // OMODE1 only
  const float* bias;
  int K;
  int lda, ldbt, ldc;
  long long sA1, sB1, sC1;    // per-z offsets (elements)
};

// ---------------- 256x192 k-half-pipelined GEMM ----------------------------
// D[m][n] = sum_k A[m][k]*BT[n][k] + bias[n].
// LDS 136 KiB shorts: A[2][256][64] at buf*16384; B[3][192][64] at 32768+bb*12288.
// Rotation swizzle both sides: LDS col' = (k + row*8)&63; fragment rows differ
// by multiples of 16 -> all read addrs = base + lof0/lof1.
// Schedule per K-tile t (one barrier): khalf0 regs preloaded at end of t-1;
// issue khalf1 reads + stage A(t+1),B(t+2); MFMA khalf0 (covers the reads);
// MFMA khalf1; vmcnt(3)+barrier; preload khalf0 of t+1 (its buffers were
// drained by this or earlier TBVs). Staging overshoots <=2 tiles into
// allocated slack (values unused).
// OMODE 1: epilogue routes by bn: [0,768) Q row-major; [768,1536) KT
// transposed; [1536,2304) VT transposed (short4 stores along t).
// OMODE 2: f32 output + bias.

#define MFMA_(a, b, c) __builtin_amdgcn_mfma_f32_16x16x32_bf16(a, b, c, 0, 0, 0)
#define TBV { asm volatile("s_waitcnt vmcnt(3)" ::: "memory");                 \
              __builtin_amdgcn_s_barrier(); asm volatile("" ::: "memory"); }

template <int OMODE>
__global__ __launch_bounds__(512, 1) void gemm1b(GemmArgs g) {
  __shared__ unsigned short L[69632];  // 136 KiB

  // bijective XCD swizzle over flattened (z,y,x); requires nwg%8==0
  const int gx = gridDim.x, gy = gridDim.y;
  const int nwg = gx * gy * gridDim.z;
  int flat = (blockIdx.z * gy + blockIdx.y) * gx + blockIdx.x;
  flat = (flat & 7) * (nwg >> 3) + (flat >> 3);
  const int gxy = gx * gy;
  const int bz = flat / gxy;
  const int rem = flat - bz * gxy;
  const int by = rem / gx;
  const int bx = rem - by * gx;

  const long long offA = bz * g.sA1;
  const long long offB = bz * g.sB1;
  const long long offC = bz * g.sC1;
  const int bm = by * 256, bn = bx * 192;

  const int tid = threadIdx.x;
  const int lane = tid & 63, wave = tid >> 6;
  const int wm = wave >> 2, wn = wave & 3;      // 2 x 4 waves; wave tile 128x48
  const int l15 = lane & 15, l4 = lane >> 4;

  // loop-invariant LDS read offsets (elements)
  const int lof0 = l15 * 64 + (((l4 + l15) * 8) & 63);
  const int lof1 = l15 * 64 + ((32 + (l4 + l15) * 8) & 63);
  const int wmA = wm * 8192;
  const int wnB = wn * 3072;

  // loop-invariant staging offsets (elements)
  int LA[4], DA[4], LB[3], DB[3];
  #pragma unroll
  for (int r = 0; r < 4; ++r) {
    const int c = tid + r * 512;
    const int row = c >> 3, j = c & 7;
    LA[r] = row * g.lda + ((j - row) & 7) * 8;
    DA[r] = c * 8;
  }
  #pragma unroll
  for (int r = 0; r < 3; ++r) {
    const int c = tid + r * 512;
    const int row = c >> 3, j = c & 7;
    LB[r] = row * g.ldbt + ((j - row) & 7) * 8;
    DB[r] = c * 8;
  }

  const unsigned short* Ab = (const unsigned short*)g.A + offA + (long long)bm * g.lda;
  const unsigned short* Bb = g.BT + offB + (long long)bn * g.ldbt;

  auto stA = [&](int bufsel, const unsigned short* p) {
    unsigned short* dst = &L[bufsel * 16384];
    #pragma unroll
    for (int r = 0; r < 4; ++r)
      __builtin_amdgcn_global_load_lds((ga_u8*)(p + LA[r]), (la_u8*)(dst + DA[r]), 16, 0, 0);
  };
  auto stB = [&](int bb, const unsigned short* p) {
    unsigned short* dst = &L[32768 + bb * 12288];
    #pragma unroll
    for (int r = 0; r < 3; ++r)
      __builtin_amdgcn_global_load_lds((ga_u8*)(p + LB[r]), (la_u8*)(dst + DB[r]), 16, 0, 0);
  };

  const f32x4 fz = {0.f, 0.f, 0.f, 0.f};
  f32x4 acc[8][3];
  #pragma unroll
  for (int i = 0; i < 8; ++i)
    #pragma unroll
    for (int j = 0; j < 3; ++j) acc[i][j] = fz;

  const unsigned short* pA = Ab;
  const unsigned short* pB = Bb;

  // prologue: A0,B0 (7), B1 (3); drain A0,B0, leave B1 in flight.
  stA(0, pA); pA += 64;
  stB(0, pB); pB += 64;
  stB(1, pB); pB += 64;
  TBV

  bf16x8 af0[8], bf0[3], af1[8], bf1[3];
#define RD_HALF(dstA, dstB, bc, br, LOF)                                       \
  {                                                                            \
    const unsigned short* As_ = &L[(bc) * 16384 + wmA];                        \
    const unsigned short* Bs_ = &L[32768 + (br) * 12288 + wnB];                \
    _Pragma("unroll")                                                          \
    for (int x = 0; x < 3; ++x) dstB[x] = *(const bf16x8*)&Bs_[x * 1024 + LOF];\
    _Pragma("unroll")                                                          \
    for (int x = 0; x < 8; ++x) dstA[x] = *(const bf16x8*)&As_[x * 1024 + LOF];\
  }

  int bufc = 0, bbr = 0, bbs = 2;
  RD_HALF(af0, bf0, 0, 0, lof0)   // preload khalf0 of tile 0

  const int NT = g.K >> 6;
  for (int t = 0; t < NT; ++t) {
    RD_HALF(af1, bf1, bufc, bbr, lof1)   // khalf1 reads, in flight under MFMA
    stA(bufc ^ 1, pA); pA += 64;         // A(t+1)
    stB(bbs, pB); pB += 64;              // B(t+2)

    __builtin_amdgcn_s_setprio(1);
    #pragma unroll
    for (int nf = 0; nf < 3; ++nf)
      #pragma unroll
      for (int rj = 0; rj < 8; ++rj)
        acc[rj][nf] = MFMA_(af0[rj], bf0[nf], acc[rj][nf]);
    #pragma unroll
    for (int nf = 0; nf < 3; ++nf)
      #pragma unroll
      for (int rj = 0; rj < 8; ++rj)
        acc[rj][nf] = MFMA_(af1[rj], bf1[nf], acc[rj][nf]);
    __builtin_amdgcn_s_setprio(0);

    TBV
    bufc ^= 1;
    bbr = (bbr == 2) ? 0 : bbr + 1;
    bbs = (bbs == 2) ? 0 : bbs + 1;
    RD_HALF(af0, bf0, bufc, bbr, lof0)   // preload khalf0 of t+1 (benign on last)
  }

  // ---- epilogue ----
  const int row0 = bm + wm * 128 + l4 * 4;
  const int col0 = wn * 48 + l15;  // col within block
  if (OMODE == 2) {
    #pragma unroll
    for (int mf = 0; mf < 8; ++mf)
      #pragma unroll
      for (int nf = 0; nf < 3; ++nf) {
        const int col = bn + col0 + nf * 16;
        const float bv = g.bias[col];
        #pragma unroll
        for (int ii = 0; ii < 4; ++ii)
          ((float*)g.C)[offC + (long long)(row0 + mf * 16 + ii) * g.ldc + col] =
              acc[mf][nf][ii] + bv;
      }
  } else if (bn < 768) {  // Q region: row-major bf16 [16384][768]
    #pragma unroll
    for (int mf = 0; mf < 8; ++mf)
      #pragma unroll
      for (int nf = 0; nf < 3; ++nf) {
        const int col = bn + col0 + nf * 16;
        const float bv = g.bias[col];
        #pragma unroll
        for (int ii = 0; ii < 4; ++ii)
          ((unsigned short*)g.C)[(long long)(row0 + mf * 16 + ii) * 768 + col] =
              f2bf(acc[mf][nf][ii] + bv);
      }
  } else {  // K/V region: transposed store [bh][64 d][1024 t]
    unsigned short* T = (bn < 1536) ? g.KT : g.VT;
    const int rbase = (bn < 1536) ? 768 : 1536;
    const int b = bm >> 10;
    const int t0 = (row0 & 1023);
    #pragma unroll
    for (int nf = 0; nf < 3; ++nf) {
      const int gcol = bn + col0 + nf * 16;
      const float bv = g.bias[gcol];
      const int cr = gcol - rbase;
      const int h = cr >> 6, d = cr & 63;
      unsigned short* Tb = T + ((long long)(b * 12 + h) * 64 + d) * 1024;
      #pragma unroll
      for (int mf = 0; mf < 8; ++mf) {
        short4v sv;
        #pragma unroll
        for (int ii = 0; ii < 4; ++ii) sv[ii] = (short)f2bf(acc[mf][nf][ii] + bv);
        *(short4v*)&Tb[t0 + mf * 16] = sv;
      }
    }
  }
}

// ---------------- ktv: Mh[bh] = KT[bh] . VT[bh]^T  (M=64,N=64,K=1024) ------
// A = KT rows d (ld 1024), BT = VT rows e (ld 1024); 4 waves, wave tile 64x16.
__global__ __launch_bounds__(256) void ktv_mfma(const unsigned short* __restrict__ KT,
                                                const unsigned short* __restrict__ VT,
                                                unsigned short* __restrict__ Mh) {
  __shared__ unsigned short L[2][2][4096];  // [buf][A/B][64 rows x 64 k] rotated
  const int z = blockIdx.x;  // bh
  const int tid = threadIdx.x;
  const int lane = tid & 63, wave = tid >> 6;
  const int l15 = lane & 15, l4 = lane >> 4;

  const int lof0 = l15 * 64 + (((l4 + l15) * 8) & 63);
  const int lof1 = l15 * 64 + ((32 + (l4 + l15) * 8) & 63);

  // staging offsets: 512 chunks of 16B per 4096-short tile -> 2 per thread
  int LS[2], DS[2];
  #pragma unroll
  for (int r = 0; r < 2; ++r) {
    const int c = tid + r * 256;
    const int row = c >> 3, j = c & 7;
    LS[r] = row * 1024 + ((j - row) & 7) * 8;
    DS[r] = c * 8;
  }
  const unsigned short* Ab = KT + (long long)z * 65536;
  const unsigned short* Bb = VT + (long long)z * 65536;

  auto stg = [&](int buf, const unsigned short* pa, const unsigned short* pb) {
    #pragma unroll
    for (int r = 0; r < 2; ++r) {
      __builtin_amdgcn_global_load_lds((ga_u8*)(pa + LS[r]), (la_u8*)(&L[buf][0][0] + DS[r]), 16, 0, 0);
      __builtin_amdgcn_global_load_lds((ga_u8*)(pb + LS[r]), (la_u8*)(&L[buf][1][0] + DS[r]), 16, 0, 0);
    }
  };

  const f32x4 fz = {0.f, 0.f, 0.f, 0.f};
  f32x4 acc[4];
  #pragma unroll
  for (int i = 0; i < 4; ++i) acc[i] = fz;

  const int eb = wave * 1024;  // B row group (e = wave*16 + l15)
  stg(0, Ab, Bb);
  for (int t = 0; t < 16; ++t) {
    asm volatile("s_waitcnt vmcnt(0)" ::: "memory");
    __builtin_amdgcn_s_barrier();
    asm volatile("" ::: "memory");
    const int buf = t & 1;
    bf16x8 bv0 = *(const bf16x8*)&L[buf][1][eb + lof0];
    bf16x8 bv1 = *(const bf16x8*)&L[buf][1][eb + lof1];
    bf16x8 a0[4], a1[4];
    #pragma unroll
    for (int mf = 0; mf < 4; ++mf) {
      a0[mf] = *(const bf16x8*)&L[buf][0][mf * 1024 + lof0];
      a1[mf] = *(const bf16x8*)&L[buf][0][mf * 1024 + lof1];
    }
    if (t < 15) stg(buf ^ 1, Ab + (t + 1) * 64, Bb + (t + 1) * 64);
    #pragma unroll
    for (int mf = 0; mf < 4; ++mf) acc[mf] = MFMA_(a0[mf], bv0, acc[mf]);
    #pragma unroll
    for (int mf = 0; mf < 4; ++mf) acc[mf] = MFMA_(a1[mf], bv1, acc[mf]);
    __builtin_amdgcn_s_barrier();
    asm volatile("" ::: "memory");
  }

  unsigned short* mb = Mh + (long long)z * 4096;
  const int e = wave * 16 + l15;
  #pragma unroll
  for (int mf = 0; mf < 4; ++mf)
    #pragma unroll
    for (int ii = 0; ii < 4; ++ii)
      mb[(mf * 16 + l4 * 4 + ii) * 64 + e] = f2bf(acc[mf][ii]);
}

// ---------------- W2T: per-(b,h) 768x64x64 GEMM ----------------------------
// C[j][d] = sum_e WoutT[j][h*64+e] * Mh[z][d][e]
__global__ __launch_bounds__(256) void gemm_w2t(const unsigned short* __restrict__ WoutT,
                                                const unsigned short* __restrict__ Mh,
                                                unsigned short* __restrict__ W2T) {
  constexpr int LDT = 72;
  __shared__ unsigned short As[128 * LDT];
  __shared__ unsigned short Bs[64 * LDT];

  const int bm = blockIdx.x * 128;
  const int z = blockIdx.y;
  const int b = z / 12, h = z % 12;
  const int tid = threadIdx.x;
  const int lane = tid & 63, wave = tid >> 6;
  const int l15 = lane & 15, l4 = lane >> 4;
  const int srow = tid >> 3, scg = (tid & 7) * 8;

  const unsigned short* Abase = WoutT + (long long)bm * 768 + h * 64;
  #pragma unroll
  for (int s = 0; s < 4; ++s) {
    const int row = s * 32 + srow;
    *(bf16x8*)&As[row * LDT + scg] =
        *(const bf16x8*)(Abase + (long long)row * 768 + scg);
  }
  #pragma unroll
  for (int s = 0; s < 2; ++s) {
    const int row = s * 32 + srow;
    *(bf16x8*)&Bs[row * LDT + scg] =
        *(const bf16x8*)(Mh + (long long)z * 4096 + row * 64 + scg);
  }
  __syncthreads();

  const f32x4 fz = {0.f, 0.f, 0.f, 0.f};
  f32x4 acc[2][4];
  #pragma unroll
  for (int i = 0; i < 2; ++i)
    #pragma unroll
    for (int j = 0; j < 4; ++j) acc[i][j] = fz;

  #pragma unroll
  for (int ks = 0; ks < 64; ks += 32) {
    const int kk = ks + l4 * 8;
    bf16x8 af[2], bfv[4];
    #pragma unroll
    for (int i = 0; i < 2; ++i)
      af[i] = *(const bf16x8*)&As[(wave * 32 + i * 16 + l15) * LDT + kk];
    #pragma unroll
    for (int i = 0; i < 4; ++i)
      bfv[i] = *(const bf16x8*)&Bs[(i * 16 + l15) * LDT + kk];
    #pragma unroll
    for (int mi = 0; mi < 2; ++mi)
      #pragma unroll
      for (int ni = 0; ni < 4; ++ni)
        acc[mi][ni] = MFMA_(af[mi], bfv[ni], acc[mi][ni]);
  }

  unsigned short* Cb = W2T + (long long)b * 589824 + h * 64;
  #pragma unroll
  for (int mi = 0; mi < 2; ++mi)
    #pragma unroll
    for (int ni = 0; ni < 4; ++ni)
      #pragma unroll
      for (int ii = 0; ii < 4; ++ii) {
        const int row = bm + wave * 32 + mi * 16 + l4 * 4 + ii;
        const int col = ni * 16 + l15;
        Cb[(long long)row * 768 + col] = f2bf(acc[mi][ni][ii]);
      }
}

// ---------------------------------------------------------------------------
extern "C" void kernel_launch(void* const* d_in, const int* in_sizes, int n_in,
                              void* d_out, int out_size, void* d_ws, size_t ws_size,
                              hipStream_t stream) {
  (void)in_sizes; (void)n_in; (void)out_size; (void)ws_size;
  const float* x    = (const float*)d_in[0];  // [16384,768]
  const float* Wqkv = (const float*)d_in[1];  // [768,2304]
  const float* bqkv = (const float*)d_in[2];  // [2304]
  const float* Wout = (const float*)d_in[3];  // [768,768]
  const float* bout = (const float*)d_in[4];  // [768]
  float* out = (float*)d_out;                 // [16384,768] f32

  char* ws = (char*)d_ws;
  size_t off = 0;
  auto carve = [&](size_t bytes) {
    char* p = ws + off;
    off += (bytes + 255) & ~(size_t)255;
    return p;
  };
  unsigned short* WqkvT = (unsigned short*)carve((size_t)2304 * 768 * 2);     // 3.5 MB
  unsigned short* WoutT = (unsigned short*)carve((size_t)768 * 768 * 2);      // 1.2 MB
  unsigned short* Qbuf  = (unsigned short*)carve((size_t)16384 * 768 * 2);    // 25.2 MB
  unsigned short* KT    = (unsigned short*)carve((size_t)192 * 64 * 1024 * 2);// 25.2 MB
  unsigned short* VT    = (unsigned short*)carve((size_t)192 * 64 * 1024 * 2);// 25.2 MB
  unsigned short* Mh    = (unsigned short*)carve((size_t)192 * 64 * 64 * 2);  // 1.6 MB
  unsigned short* xbf   = (unsigned short*)carve((size_t)16384 * 768 * 2);    // 25.2 MB
  unsigned short* W2T   = xbf;  // aliases xbf (dead after gemm1); 18 MB fits
  carve((size_t)1 << 18);       // 256 KB slack for staging-pointer overshoot
  // total ~108 MB of d_ws

  cvt_f32_bf16<<<dim3(16384 * 768 / 8 / 256), 256, 0, stream>>>(x, xbf);
  transpose_cvt<<<dim3(2304 / 32, 768 / 32), 256, 0, stream>>>(Wqkv, WqkvT, 768, 2304);
  transpose_cvt<<<dim3(768 / 32, 768 / 32), 256, 0, stream>>>(Wout, WoutT, 768, 768);

  // 1) {Q, KT, VT} = xbf @ Wqkv + b_qkv   (grid 12*64=768 = 3 exact rounds)
  GemmArgs g1{};
  g1.A = xbf; g1.BT = WqkvT; g1.C = Qbuf; g1.KT = KT; g1.VT = VT; g1.bias = bqkv;
  g1.K = 768; g1.lda = 768; g1.ldbt = 768; g1.ldc = 768;
  gemm1b<1><<<dim3(12, 64, 1), 512, 0, stream>>>(g1);

  // 2) Mh[bh] = KT[bh] . VT[bh]^T
  ktv_mfma<<<dim3(192), 256, 0, stream>>>(KT, VT, Mh);

  // 3) W2T[b][j][h*64+d] = sum_e WoutT[j][h*64+e] * Mh[bh][d][e]
  gemm_w2t<<<dim3(6, 192), 256, 0, stream>>>(WoutT, Mh, W2T);

  // 4) out[b] = Q[b] @ W2[b] + b_out  (grid 4*4*16=256, %8==0)
  GemmArgs g3{};
  g3.A = Qbuf; g3.BT = W2T; g3.C = out; g3.bias = bout;
  g3.K = 768; g3.lda = 768; g3.ldbt = 768; g3.ldc = 768;
  g3.sA1 = 786432;   // 1024*768
  g3.sB1 = 589824;   // 768*768
  g3.sC1 = 786432;   // 1024*768
  gemm1b<2><<<dim3(4, 4, 16), 512, 0, stream>>>(g3);
}